// Round 1
// baseline (1126.791 us; speedup 1.0000x reference)
//
#include <hip/hip_runtime.h>
#include <hip/hip_fp16.h>

#define NROWS 32768
#define DDIM  2048
#define BN_EPS 1e-3f

typedef _Float16 f16;
typedef _Float16 f16x4 __attribute__((ext_vector_type(4)));
typedef _Float16 f16x8 __attribute__((ext_vector_type(8)));
typedef float    f32x4 __attribute__((ext_vector_type(4)));

// ---------------------------------------------------------------- fast tanh
// tanh(x) = 1 - 2/(1+exp(2x)); v_exp_f32 path, accurate to ~2 ulp.
__device__ __forceinline__ float fast_tanh(float x) {
  float e = __expf(2.0f * x);
  return 1.0f - __fdividef(2.0f, e + 1.0f);
}

// ------------------------------------------------- async global->LDS (16 B)
__device__ __forceinline__ void async_copy16(void* lds, const void* g) {
  __builtin_amdgcn_global_load_lds(
      (const __attribute__((address_space(1))) void*)g,
      (__attribute__((address_space(3))) void*)lds,
      16, 0, 0);
}

// ---------------------------------------------------------------- kernel 1
// inv[d] = gamma/sqrt(var+eps); bias[d] = beta - mean*inv
__global__ void bnparams(const float* __restrict__ gamma, const float* __restrict__ beta,
                         const float* __restrict__ mean, const float* __restrict__ var,
                         float* __restrict__ inv, float* __restrict__ bias) {
  int d = blockIdx.x * blockDim.x + threadIdx.x;
  if (d < DDIM) {
    float iv = gamma[d] / sqrtf(var[d] + BN_EPS);
    inv[d]  = iv;
    bias[d] = beta[d] - mean[d] * iv;
  }
}

// ---------------------------------------------------------------- kernel 2
// h1 = BN(x1) in fp16 (A operand of GEMM + epilogue h1)
__global__ void h1conv(const float4* __restrict__ x1, const float4* __restrict__ inv4,
                       const float4* __restrict__ bias4, f16x4* __restrict__ h1) {
  const int total = NROWS * (DDIM / 4);
  int idx = blockIdx.x * blockDim.x + threadIdx.x;
  int stride = gridDim.x * blockDim.x;
  for (int i = idx; i < total; i += stride) {
    float4 x = x1[i];
    int c4 = i & (DDIM / 4 - 1);
    float4 iv = inv4[c4], bs = bias4[c4];
    f16x4 h;
    h.x = (f16)fmaf(x.x, iv.x, bs.x);
    h.y = (f16)fmaf(x.y, iv.y, bs.y);
    h.z = (f16)fmaf(x.z, iv.z, bs.z);
    h.w = (f16)fmaf(x.w, iv.w, bs.w);
    h1[i] = h;
  }
}

// ---------------------------------------------------------------- kernel 3
// Wt[j][k] = (f16) W[k][j]   (LDS-tiled transpose)
__global__ void wtrans(const float* __restrict__ W, f16* __restrict__ Wt) {
  __shared__ float t[32][33];
  int j0 = blockIdx.x * 32, k0 = blockIdx.y * 32;
  int tx = threadIdx.x, ty = threadIdx.y;  // 32 x 8
#pragma unroll
  for (int r = 0; r < 32; r += 8)
    t[ty + r][tx] = W[(size_t)(k0 + ty + r) * DDIM + j0 + tx];
  __syncthreads();
#pragma unroll
  for (int r = 0; r < 32; r += 8)
    Wt[(size_t)(j0 + ty + r) * DDIM + k0 + tx] = (f16)t[tx][ty + r];
}

// ---------------------------------------------------------------- kernel 4
// z = h1 @ W via fp16 MFMA, fused epilogue:
// gate = relu(tanh(z)); out = tanh(h2 + gate*(h1-h2)), h2 = BN(x2)
__global__ __launch_bounds__(256)
void gemm_fused(const f16* __restrict__ Ah, const f16* __restrict__ Bt,
                const float* __restrict__ x2, const float* __restrict__ invv,
                const float* __restrict__ biasv, float* __restrict__ out) {
  // [buf][A/B][128 rows x 32 k] fp16, 8 KB per tile, 32 KB total
  __shared__ __align__(16) f16 sm[2][2][128 * 32];

  const int tid  = threadIdx.x;
  const int lane = tid & 63;
  const int wave = tid >> 6;
  const int wrow = wave >> 1, wcol = wave & 1;  // 2x2 wave grid, 64x64 each

  // XCD-aware swizzle: xcd = bid&7 gets contiguous chunk; within chunk
  // m-inner (32 m-panels) so the B column-panel stays L2-resident.
  int bid  = blockIdx.x;
  int xcd  = bid & 7;
  int c    = bid >> 3;              // 0..511
  int mblk = xcd * 32 + (c & 31);   // 0..255
  int nblk = c >> 5;                // 0..15
  const int bm = mblk * 128, bn = nblk * 128;

  f32x4 acc[4][4];
#pragma unroll
  for (int m = 0; m < 4; ++m)
#pragma unroll
    for (int n = 0; n < 4; ++n)
      acc[m][n] = (f32x4){0.f, 0.f, 0.f, 0.f};

  // stage one 128x32 fp16 tile: 512 chunks of 16 B, 2 per thread.
  // 16B-chunk XOR swizzle: LDS slot s holds global kq = s ^ ((row>>1)&3)
  // -> ds_read_b128 lands 2-way per bank (free).
  auto stage = [&](f16* lds, const f16* gbase) {
#pragma unroll
    for (int p = 0; p < 2; ++p) {
      int chunk = p * 256 + tid;
      int row   = chunk >> 2;
      int slot  = chunk & 3;
      int kq    = slot ^ ((row >> 1) & 3);
      async_copy16(lds + chunk * 8, gbase + (size_t)row * DDIM + kq * 8);
    }
  };

  const f16* Abase = Ah + (size_t)bm * DDIM;
  const f16* Bbase = Bt + (size_t)bn * DDIM;

  stage(sm[0][0], Abase);
  stage(sm[0][1], Bbase);
  __syncthreads();

  const int r16 = lane & 15;
  const int kq  = lane >> 4;
  const int sw  = ((r16 >> 1) & 3) ^ kq;           // swizzled 16B slot
  const int aoffA = (wrow * 64 + r16) * 32 + sw * 8;  // fp16 units
  const int aoffB = (wcol * 64 + r16) * 32 + sw * 8;

  int cur = 0;
  const int NT = DDIM / 32;  // 64 K-steps
  for (int t = 0; t < NT; ++t) {
    if (t + 1 < NT) {
      stage(sm[cur ^ 1][0], Abase + (t + 1) * 32);
      stage(sm[cur ^ 1][1], Bbase + (t + 1) * 32);
    }
    const f16* As = sm[cur][0];
    const f16* Bs = sm[cur][1];
    f16x8 af[4], bf[4];
#pragma unroll
    for (int m = 0; m < 4; ++m)
      af[m] = *(const f16x8*)(As + aoffA + m * 16 * 32);
#pragma unroll
    for (int n = 0; n < 4; ++n)
      bf[n] = *(const f16x8*)(Bs + aoffB + n * 16 * 32);
#pragma unroll
    for (int m = 0; m < 4; ++m)
#pragma unroll
      for (int n = 0; n < 4; ++n)
        acc[m][n] = __builtin_amdgcn_mfma_f32_16x16x32_f16(af[m], bf[n], acc[m][n], 0, 0, 0);
    __syncthreads();
    cur ^= 1;
  }

  // epilogue: D frag layout col = lane&15, row = (lane>>4)*4 + i
  const int rq = lane >> 4;
#pragma unroll
  for (int n = 0; n < 4; ++n) {
    int col = bn + wcol * 64 + n * 16 + r16;
    float iv = invv[col], bs = biasv[col];
#pragma unroll
    for (int m = 0; m < 4; ++m) {
      int row0 = bm + wrow * 64 + m * 16 + rq * 4;
#pragma unroll
      for (int i = 0; i < 4; ++i) {
        int r = row0 + i;
        size_t off = (size_t)r * DDIM + col;
        float z = acc[m][n][i];
        float g = fmaxf(fast_tanh(z), 0.0f);
        float h2 = fmaf(x2[off], iv, bs);
        float h1v = (float)Ah[off];
        float o = fmaf(g, h1v - h2, h2);
        out[off] = fast_tanh(o);
      }
    }
  }
}

// ---------------------------------------------------------------- launch
extern "C" void kernel_launch(void* const* d_in, const int* in_sizes, int n_in,
                              void* d_out, int out_size, void* d_ws, size_t ws_size,
                              hipStream_t stream) {
  const float* x1    = (const float*)d_in[0];
  const float* x2    = (const float*)d_in[1];
  const float* W     = (const float*)d_in[2];
  const float* gamma = (const float*)d_in[3];
  const float* beta  = (const float*)d_in[4];
  const float* mean  = (const float*)d_in[5];
  const float* var   = (const float*)d_in[6];
  float* out = (float*)d_out;

  char* ws = (char*)d_ws;
  float* inv  = (float*)ws;               // 8 KB
  float* bias = (float*)(ws + 8192);      // 8 KB
  f16* wt = (f16*)(ws + 16384);           // 8 MB
  f16* h1 = (f16*)(ws + 16384 + (size_t)DDIM * DDIM * 2);  // 128 MB

  bnparams<<<DDIM / 256, 256, 0, stream>>>(gamma, beta, mean, var, inv, bias);
  h1conv<<<2048, 256, 0, stream>>>((const float4*)x1, (const float4*)inv,
                                   (const float4*)bias, (f16x4*)h1);
  wtrans<<<dim3(DDIM / 32, DDIM / 32), dim3(32, 8), 0, stream>>>(W, wt);
  gemm_fused<<<(NROWS / 128) * (DDIM / 128), 256, 0, stream>>>(h1, wt, x2, inv, bias, out);
}